// Round 19
// baseline (482.370 us; speedup 1.0000x reference)
//
#include <hip/hip_runtime.h>
#include <hip/hip_bf16.h>

#define BB 16
#define CC 192
#define HH 96
#define WWW 96
#define HWSZ 9216
#define DKC 64

typedef __hip_bfloat16 bf16;
typedef __attribute__((ext_vector_type(8))) short s8v;
typedef __attribute__((ext_vector_type(4))) float f32x4;

__device__ __forceinline__ float bf2f(unsigned short u) {
  union { unsigned int i; float f; } x; x.i = ((unsigned int)u) << 16; return x.f;
}
__device__ __forceinline__ unsigned short f2bf(float f) {
  union { __hip_bfloat16 h; unsigned short u; } c; c.h = __float2bfloat16(f); return c.u;
}

// ---------------- prep: w_out [oc][c][ky][kx] -> wb9T [sh][oc][c] bf16 ----------------
__global__ __launch_bounds__(256) void prep_w_kernel(const float* __restrict__ w_out,
                                                     unsigned short* __restrict__ wb9T) {
  int e = blockIdx.x * 256 + threadIdx.x;
  if (e >= 9 * CC * CC) return;
  int c = e % CC;
  int oc = (e / CC) % CC;
  int sh = e / (CC * CC);
  wb9T[e] = f2bf(w_out[((size_t)(oc * CC + c)) * 9 + sh]);
}

// ---------------- prep: wq/wk/wv fp32 -> wqkv [sel][oc][c] bf16 ----------------
__global__ __launch_bounds__(256) void prep_wqkv_kernel(
    const float* __restrict__ wq, const float* __restrict__ wk, const float* __restrict__ wv,
    unsigned short* __restrict__ wqkv) {
  int e = blockIdx.x * 256 + threadIdx.x;
  if (e >= 3 * CC * CC) return;
  int sel = e / (CC * CC), r = e % (CC * CC);
  const float* w = sel == 0 ? wq : sel == 1 ? wk : wv;
  wqkv[e] = f2bf(w[r]);
}

// ---------------- QKV v6: block=(b,h); fused x NCHW->NHWC staging; 3-pass vt epilogue ----
#define VTS 232
__global__ __launch_bounds__(256) void qkv_mfma_kernel(
    const float* __restrict__ x, const unsigned short* __restrict__ wqkv,
    const float* __restrict__ bq, const float* __restrict__ bk, const float* __restrict__ bv,
    unsigned short* __restrict__ q, unsigned short* __restrict__ k,
    unsigned short* __restrict__ v) {
  __shared__ unsigned short xl[96 * 200];   // [pix][192 ch + pad8]  (38400 B)
  __shared__ unsigned short vt[32 * VTS];   // transpose buffer      (14848 B) -> 53 KB total
  const int tid = threadIdx.x;
  const int bid = (blockIdx.x & 7) * 192 + (blockIdx.x >> 3);  // XCD swizzle (1536/8=192)
  const int h = bid % HH;
  const int b = bid / HH;
  const int lane = tid & 63, wid = tid >> 6;
  const int lr = lane & 15, hi8 = (lane >> 4) * 8, rowb = (lane >> 4) * 4;
  const int n0 = wid * 48;
  const float* xf = x + (size_t)b * CC * HWSZ + h * WWW;

  // fused stage: x NCHW fp32 -> xl [pix][c] bf16.  192 ch x 24 float4 = 4608 = 18*256 exact.
  for (int u = tid; u < 4608; u += 256) {
    int c = u / 24, seg = u % 24;
    float4 t4 = *(const float4*)(xf + (size_t)c * HWSZ + seg * 4);
    int p0 = seg * 4;
    xl[(p0 + 0) * 200 + c] = f2bf(t4.x);
    xl[(p0 + 1) * 200 + c] = f2bf(t4.y);
    xl[(p0 + 2) * 200 + c] = f2bf(t4.z);
    xl[(p0 + 3) * 200 + c] = f2bf(t4.w);
  }
  __syncthreads();

  for (int sel = 0; sel < 3; ++sel) {
    const unsigned short* wsel = wqkv + (size_t)sel * CC * CC;
    f32x4 acc[6][3];
    #pragma unroll
    for (int mt = 0; mt < 6; ++mt)
      #pragma unroll
      for (int nt = 0; nt < 3; ++nt) acc[mt][nt] = (f32x4){0.f, 0.f, 0.f, 0.f};

    auto loadB = [&](int ck, s8v (&dst)[3]) {
      const unsigned short* src = wsel + ck * 32 + hi8;
      #pragma unroll
      for (int nt = 0; nt < 3; ++nt)
        dst[nt] = *(const s8v*)(src + (size_t)(n0 + nt * 16 + lr) * CC);
    };
    auto loadA = [&](int ck, s8v (&dst)[6]) {
      #pragma unroll
      for (int mt = 0; mt < 6; ++mt)
        dst[mt] = *(const s8v*)(xl + (mt * 16 + lr) * 200 + ck * 32 + hi8);
    };
    auto qstep = [&](int ck, s8v (&slot)[3], s8v (&acur)[6], s8v (&anxt)[6]) {
      if (ck < 5) loadA(ck + 1, anxt);
      #pragma unroll
      for (int mt = 0; mt < 6; ++mt)
        #pragma unroll
        for (int nt = 0; nt < 3; ++nt)
          acc[mt][nt] = __builtin_amdgcn_mfma_f32_16x16x32_bf16(acur[mt], slot[nt], acc[mt][nt], 0, 0, 0);
      if (ck + 3 < 6) loadB(ck + 3, slot);
    };

    s8v br0[3], br1[3], br2[3], aA[6], aB[6];
    loadB(0, br0); loadB(1, br1); loadB(2, br2);
    loadA(0, aA);
    qstep(0, br0, aA, aB);
    qstep(1, br1, aB, aA);
    qstep(2, br2, aA, aB);
    qstep(3, br0, aB, aA);
    qstep(4, br1, aA, aB);
    qstep(5, br2, aB, aA);

    // epilogue: bias + 3-pass transpose through vt (32 pixels = 2 frags per pass)
    const float* bsel = (sel == 0 ? bq : sel == 1 ? bk : bv);
    float bias[3];
    #pragma unroll
    for (int nt = 0; nt < 3; ++nt) bias[nt] = bsel[n0 + nt * 16 + lr];
    unsigned short* dst = (sel == 0 ? q : sel == 1 ? k : v) + ((size_t)(b * HWSZ + h * WWW)) * CC;
    #pragma unroll
    for (int pass = 0; pass < 3; ++pass) {
      __syncthreads();  // vt free (previous pass/sel readers done)
      #pragma unroll
      for (int mt2 = 0; mt2 < 2; ++mt2)
        #pragma unroll
        for (int nt = 0; nt < 3; ++nt)
          #pragma unroll
          for (int i = 0; i < 4; ++i)
            vt[(mt2 * 16 + rowb + i) * VTS + n0 + nt * 16 + lr] =
                f2bf(acc[pass * 2 + mt2][nt][i] + bias[nt]);
      __syncthreads();
      #pragma unroll
      for (int ii = 0; ii < 3; ++ii) {
        int e = tid + ii * 256;
        int p = e % 32, cg = e / 32;
        *(uint4*)(dst + (size_t)(pass * 32 + p) * CC + cg * 8) = *(uint4*)(vt + p * VTS + cg * 8);
      }
    }
  }
}

// ---------------- scores via MFMA: P x P GEMM over K=(rs,ch); no LDS, direct gather ------
template <int HS, int WS, int OH, int OW, int IDX>
__global__ __launch_bounds__(256) void scores_mfma_kernel(
    const unsigned short* __restrict__ q, const unsigned short* __restrict__ k,
    float* __restrict__ scores) {
  constexpr int P = HS * WS;
  constexpr int NPOS = OH * OW;
  constexpr int SLABS = 64;
  constexpr int STRIDE = SLABS * 4;
  const int slab = blockIdx.x % SLABS;
  const int b = blockIdx.x / SLABS;
  const int wid = threadIdx.x >> 6;
  const int lane = threadIdx.x & 63;
  const int lr = lane & 15, g8 = (lane >> 4) * 8;
  const int p = (lr < P) ? lr : 0;            // clamp unused rows (same-address broadcast)
  const int pixoff = (p / WS) * WWW + (p % WS);
  const unsigned short* qb = q + (size_t)b * HWSZ * CC + IDX * 64 + g8;
  const unsigned short* kb = k + (size_t)b * HWSZ * CC + IDX * 64 + g8;

  f32x4 acc = (f32x4){0.f, 0.f, 0.f, 0.f};
  int rs = slab * 4 + wid;
  if (rs < NPOS) {
    s8v aq0, aq1, bk0, bk1;
    {
      int r = rs / OW, s = rs - r * OW;
      size_t pix = (size_t)(r * HS * WWW + s * WS + pixoff) * CC;
      aq0 = *(const s8v*)(qb + pix);
      aq1 = *(const s8v*)(qb + pix + 32);
      bk0 = *(const s8v*)(kb + pix);
      bk1 = *(const s8v*)(kb + pix + 32);
    }
    for (;;) {
      int nrs = rs + STRIDE;
      s8v nq0, nq1, nk0, nk1;
      if (nrs < NPOS) {
        int r = nrs / OW, s = nrs - r * OW;
        size_t pix = (size_t)(r * HS * WWW + s * WS + pixoff) * CC;
        nq0 = *(const s8v*)(qb + pix);
        nq1 = *(const s8v*)(qb + pix + 32);
        nk0 = *(const s8v*)(kb + pix);
        nk1 = *(const s8v*)(kb + pix + 32);
      }
      acc = __builtin_amdgcn_mfma_f32_16x16x32_bf16(aq0, bk0, acc, 0, 0, 0);
      acc = __builtin_amdgcn_mfma_f32_16x16x32_bf16(aq1, bk1, acc, 0, 0, 0);
      if (nrs >= NPOS) break;
      aq0 = nq0; aq1 = nq1; bk0 = nk0; bk1 = nk1;
      rs = nrs;
    }
  }
  const int col = lane & 15;
  const int row0 = (lane >> 4) * 4;
  if (col < P) {
    float* sc = scores + (IDX * BB + b) * 256;
    #pragma unroll
    for (int i = 0; i < 4; ++i) {
      int row = row0 + i;
      if (row < P) atomicAdd(sc + row * P + col, acc[i]);
    }
  }
}

// ---------------- softmax over P ----------------
__global__ void softmax_kernel(const float* __restrict__ scores, float* __restrict__ probs) {
  int t = threadIdx.x;
  int idx, b, p, P; float scale;
  if (t < 64)       { idx = 0; b = t >> 2;           p = t & 3;         P = 4;  scale = 1.f / 384.f; }
  else if (t < 208) { int u = t - 64;  idx = 1; b = u / 9;  p = u % 9;  P = 9;  scale = 1.f / 256.f; }
  else if (t < 464) { int u = t - 208; idx = 2; b = u >> 4; p = u & 15; P = 16; scale = 1.f / 192.f; }
  else return;
  const float* row = scores + (idx * BB + b) * 256 + p * P;
  float* orow = probs + (idx * BB + b) * 256 + p * P;
  float vals[16];
  float m = -1e30f;
  for (int i = 0; i < P; i++) { vals[i] = row[i] * scale; m = fmaxf(m, vals[i]); }
  float s = 0.f;
  for (int i = 0; i < P; i++) { vals[i] = expf(vals[i] - m); s += vals[i]; }
  float inv = 1.f / s;
  for (int i = 0; i < P; i++) orow[i] = vals[i] * inv;
}

// ---------------- PV + unstitch: block = (b, r); v/attn NHWC ----------------
template <int HS, int WS, int OH, int OW, int IDX>
__global__ __launch_bounds__(256) void pv_kernel(
    const unsigned short* __restrict__ v, const float* __restrict__ probs,
    unsigned short* __restrict__ attn) {
  constexpr int P = HS * WS;
  __shared__ unsigned short vl[HS * 96 * 72];  // [iq][col][c(64)+pad8]
  __shared__ float pl[P * P];
  int b = blockIdx.x / OH;
  int r = blockIdx.x % OH;
  const int tid = threadIdx.x;
  for (int u = tid; u < HS * 96 * 8; u += 256) {
    int iq = u / 768, w = (u >> 3) % 96, cg = u & 7;
    *(uint4*)(vl + (iq * 96 + w) * 72 + cg * 8) =
        *(const uint4*)(v + ((size_t)(b * HWSZ + (r * HS + iq) * WWW + w)) * CC + IDX * 64 + cg * 8);
  }
  if (tid < P * P) pl[tid] = probs[(IDX * BB + b) * 256 + tid];
  __syncthreads();
  for (int u = tid; u < HS * 96 * 8; u += 256) {
    int i = u / 768, w = (u >> 3) % 96, cg = u & 7;
    int j = w / OW, s = w - j * OW;
    int p = i * WS + j;
    float acc[8];
    #pragma unroll
    for (int m = 0; m < 8; ++m) acc[m] = 0.f;
    #pragma unroll
    for (int iq = 0; iq < HS; ++iq) {
      #pragma unroll
      for (int jq = 0; jq < WS; ++jq) {
        float pw = pl[p * P + iq * WS + jq];
        s8v vv = *(const s8v*)(vl + (iq * 96 + s * WS + jq) * 72 + cg * 8);
        #pragma unroll
        for (int m = 0; m < 8; ++m) acc[m] += pw * bf2f((unsigned short)vv[m]);
      }
    }
    uint4 ov;
    ov.x = (unsigned int)f2bf(acc[0]) | ((unsigned int)f2bf(acc[1]) << 16);
    ov.y = (unsigned int)f2bf(acc[2]) | ((unsigned int)f2bf(acc[3]) << 16);
    ov.z = (unsigned int)f2bf(acc[4]) | ((unsigned int)f2bf(acc[5]) << 16);
    ov.w = (unsigned int)f2bf(acc[6]) | ((unsigned int)f2bf(acc[7]) << 16);
    *(uint4*)(attn + ((size_t)(b * HWSZ + (i * OH + r) * WWW + w)) * CC + IDX * 64 + cg * 8) = ov;
  }
}

// ---------------- conv3x3: single-buffer A (24 KB), B ring-3, no forced bounds ----------
__global__ __launch_bounds__(256) void conv_mfma_kernel(
    const unsigned short* __restrict__ attn, const unsigned short* __restrict__ wb9T,
    const float* __restrict__ b_out, unsigned short* __restrict__ ybf,
    float* __restrict__ bnsum, float* __restrict__ bnsqs) {
  __shared__ unsigned short al[3 * 98 * 40];  // [ky][w+halo][c32 + pad8] = 23520 B
  const int tid = threadIdx.x;
  const int bid = (blockIdx.x & 7) * 192 + (blockIdx.x >> 3);  // XCD swizzle (1536/8=192)
  const int h = bid % HH;
  const int b = bid / HH;
  const int lane = tid & 63, wid = tid >> 6;
  const int lr = lane & 15, hi8 = (lane >> 4) * 8, rowb = (lane >> 4) * 4;
  const int n0 = wid * 48;

  f32x4 acc[6][3];
  #pragma unroll
  for (int mt = 0; mt < 6; ++mt)
    #pragma unroll
    for (int nt = 0; nt < 3; ++nt) acc[mt][nt] = (f32x4){0.f, 0.f, 0.f, 0.f};

  uint4 aregs[5];
  auto stageA_LOAD = [&](int chunk) {
    int c0 = chunk * 32;
    #pragma unroll
    for (int i = 0; i < 5; ++i) {
      int u = tid + i * 256;
      if (u < 1176) {
        int row = u / 392, rem = u % 392, wx = rem >> 2, qq = rem & 3;
        int hr = h + row - 1, w = wx - 1;
        uint4 val = make_uint4(0u, 0u, 0u, 0u);
        if (hr >= 0 && hr < HH && w >= 0 && w < WWW)
          val = *(const uint4*)(attn + ((size_t)(b * HWSZ + hr * WWW + w)) * CC + c0 + qq * 8);
        aregs[i] = val;
      }
    }
  };
  auto stageA_WRITE = [&]() {
    #pragma unroll
    for (int i = 0; i < 5; ++i) {
      int u = tid + i * 256;
      if (u < 1176) {
        int row = u / 392, rem = u % 392, wx = rem >> 2, qq = rem & 3;
        *(uint4*)(al + (row * 98 + wx) * 40 + qq * 8) = aregs[i];
      }
    }
  };
  auto loadB = [&](int it2, s8v (&dst)[3]) {
    int chunk = it2 / 9, sh = it2 % 9;
    const unsigned short* src = wb9T + (size_t)sh * CC * CC + chunk * 32 + hi8;
    #pragma unroll
    for (int nt = 0; nt < 3; ++nt)
      dst[nt] = *(const s8v*)(src + (size_t)(n0 + nt * 16 + lr) * CC);
  };

  s8v br0[3], br1[3], br2[3];
  stageA_LOAD(0);
  stageA_WRITE();
  loadB(0, br0); loadB(1, br1); loadB(2, br2);
  __syncthreads();

  auto step = [&](int chunk, int sh, s8v (&slot)[3]) {
    if (sh == 0 && chunk < 5) stageA_LOAD(chunk + 1);
    int ky = sh / 3, kx = sh % 3;
    s8v a[6];
    #pragma unroll
    for (int mt = 0; mt < 6; ++mt)
      a[mt] = *(const s8v*)(al + (ky * 98 + mt * 16 + lr + kx) * 40 + hi8);
    #pragma unroll
    for (int mt = 0; mt < 6; ++mt)
      #pragma unroll
      for (int nt = 0; nt < 3; ++nt)
        acc[mt][nt] = __builtin_amdgcn_mfma_f32_16x16x32_bf16(a[mt], slot[nt], acc[mt][nt], 0, 0, 0);
    int it = chunk * 9 + sh;
    if (it + 3 < 54) loadB(it + 3, slot);
  };

  for (int chunk = 0; chunk < 6; ++chunk) {
    step(chunk, 0, br0);
    step(chunk, 1, br1);
    step(chunk, 2, br2);
    step(chunk, 3, br0);
    step(chunk, 4, br1);
    step(chunk, 5, br2);
    step(chunk, 6, br0);
    step(chunk, 7, br1);
    step(chunk, 8, br2);
    if (chunk < 5) {
      __syncthreads();        // all waves done reading al for this chunk
      stageA_WRITE();         // overwrite with next chunk
      __syncthreads();        // writes visible
    }
  }

  // epilogue: bias, bf16 y store (NCHW), BN partial sums
  #pragma unroll
  for (int nt = 0; nt < 3; ++nt) {
    int oc = n0 + nt * 16 + lr;
    float bias = b_out[oc];
    float s1 = 0.f, s2 = 0.f;
    #pragma unroll
    for (int mt = 0; mt < 6; ++mt) {
      float v0 = acc[mt][nt][0] + bias;
      float v1 = acc[mt][nt][1] + bias;
      float v2 = acc[mt][nt][2] + bias;
      float v3 = acc[mt][nt][3] + bias;
      s1 += v0 + v1 + v2 + v3;
      s2 += v0 * v0 + v1 * v1 + v2 * v2 + v3 * v3;
      uint2 pk;
      pk.x = (unsigned int)f2bf(v0) | ((unsigned int)f2bf(v1) << 16);
      pk.y = (unsigned int)f2bf(v2) | ((unsigned int)f2bf(v3) << 16);
      *(uint2*)(ybf + ((size_t)(b * CC + oc)) * HWSZ + h * WWW + mt * 16 + rowb) = pk;
    }
    s1 += __shfl_down(s1, 32);
    s1 += __shfl_down(s1, 16);
    s2 += __shfl_down(s2, 32);
    s2 += __shfl_down(s2, 16);
    if (lane < 16) {
      atomicAdd(bnsum + oc, s1);
      atomicAdd(bnsqs + oc, s2);
    }
  }
}

// ---------------- BN finalize ----------------
__global__ void bnfin_kernel(const float* __restrict__ bnsum, const float* __restrict__ bnsqs,
                             const float* __restrict__ gamma, const float* __restrict__ beta,
                             float* __restrict__ scale, float* __restrict__ shift) {
  int c = threadIdx.x;
  if (c >= CC) return;
  const float n = 16.f * 9216.f;
  float mean = bnsum[c] / n;
  float var = bnsqs[c] / n - mean * mean;
  float inv = rsqrtf(var + 1e-5f);
  float sc = gamma[c] * inv;
  scale[c] = sc;
  shift[c] = beta[c] - mean * sc;
}

// ---------------- BN apply + LeakyReLU: ybf bf16 -> d_out fp32 ----------------
__global__ __launch_bounds__(256) void bnapply_kernel(const unsigned short* __restrict__ ybf,
                                                      float* __restrict__ y,
                                                      const float* __restrict__ scale,
                                                      const float* __restrict__ shift) {
  const int total8 = BB * CC * HWSZ / 8;
  for (int e = blockIdx.x * 256 + threadIdx.x; e < total8; e += gridDim.x * 256) {
    uint4 t = ((const uint4*)ybf)[e];
    const unsigned short* u = (const unsigned short*)&t;
    int oc = (e / (HWSZ / 8)) % CC;
    float sc = scale[oc], sh = shift[oc];
    float4 o0, o1;
    float w;
    w = bf2f(u[0]) * sc + sh; o0.x = w >= 0.f ? w : 0.2f * w;
    w = bf2f(u[1]) * sc + sh; o0.y = w >= 0.f ? w : 0.2f * w;
    w = bf2f(u[2]) * sc + sh; o0.z = w >= 0.f ? w : 0.2f * w;
    w = bf2f(u[3]) * sc + sh; o0.w = w >= 0.f ? w : 0.2f * w;
    w = bf2f(u[4]) * sc + sh; o1.x = w >= 0.f ? w : 0.2f * w;
    w = bf2f(u[5]) * sc + sh; o1.y = w >= 0.f ? w : 0.2f * w;
    w = bf2f(u[6]) * sc + sh; o1.z = w >= 0.f ? w : 0.2f * w;
    w = bf2f(u[7]) * sc + sh; o1.w = w >= 0.f ? w : 0.2f * w;
    ((float4*)y)[e * 2] = o0;
    ((float4*)y)[e * 2 + 1] = o1;
  }
}

extern "C" void kernel_launch(void* const* d_in, const int* in_sizes, int n_in,
                              void* d_out, int out_size, void* d_ws, size_t ws_size,
                              hipStream_t stream) {
  const float* x     = (const float*)d_in[0];
  const float* wq    = (const float*)d_in[1];
  const float* bq    = (const float*)d_in[2];
  const float* wk    = (const float*)d_in[3];
  const float* bk    = (const float*)d_in[4];
  const float* wv    = (const float*)d_in[5];
  const float* bv    = (const float*)d_in[6];
  const float* w_out = (const float*)d_in[7];
  const float* b_out = (const float*)d_in[8];
  const float* gamma = (const float*)d_in[9];
  const float* beta  = (const float*)d_in[10];

  char* ws = (char*)d_ws;
  const size_t TB = (size_t)BB * CC * HWSZ * sizeof(bf16);   // 56,623,104 B per tensor
  unsigned short* q    = (unsigned short*)(ws);               // NHWC bf16; later reused as ybf
  unsigned short* ybf  = q;                                   // y bf16 NCHW (q dead after scores)
  unsigned short* k    = (unsigned short*)(ws + TB);          // NHWC bf16
  unsigned short* v    = (unsigned short*)(ws + 2 * TB);      // NHWC bf16
  unsigned short* attn = (unsigned short*)(ws + 3 * TB);      // NHWC bf16
  unsigned short* wb9T = (unsigned short*)(ws + 4 * TB);      // [9][192][192] bf16
  unsigned short* wqkv = (unsigned short*)(ws + 4 * TB + 663552);  // [3][192][192] bf16
  float* scores = (float*)(ws + 4 * TB + 663552 + 221184);
  float* bnsum  = scores + 3 * BB * 256;
  float* bnsqs  = bnsum + CC;
  float* probs  = bnsqs + CC;
  float* scale  = probs + 3 * BB * 256;
  float* shift  = scale + CC;
  float* y = (float*)d_out;

  // zero scores + bn partials (contiguous)
  hipMemsetAsync(scores, 0, 49152 + 2 * CC * 4, stream);

  prep_w_kernel<<<(9 * CC * CC + 255) / 256, 256, 0, stream>>>(w_out, wb9T);
  prep_wqkv_kernel<<<(3 * CC * CC + 255) / 256, 256, 0, stream>>>(wq, wk, wv, wqkv);

  qkv_mfma_kernel<<<BB * HH, 256, 0, stream>>>(x, wqkv, bq, bk, bv, q, k, v);

  scores_mfma_kernel<2, 2, 48, 48, 0><<<BB * 64, 256, 0, stream>>>(q, k, scores);
  scores_mfma_kernel<3, 3, 32, 32, 1><<<BB * 64, 256, 0, stream>>>(q, k, scores);
  scores_mfma_kernel<4, 4, 24, 24, 2><<<BB * 64, 256, 0, stream>>>(q, k, scores);

  softmax_kernel<<<1, 512, 0, stream>>>(scores, probs);

  pv_kernel<2, 2, 48, 48, 0><<<BB * 48, 256, 0, stream>>>(v, probs, attn);
  pv_kernel<3, 3, 32, 32, 1><<<BB * 32, 256, 0, stream>>>(v, probs, attn);
  pv_kernel<4, 4, 24, 24, 2><<<BB * 24, 256, 0, stream>>>(v, probs, attn);

  conv_mfma_kernel<<<BB * HH, 256, 0, stream>>>(attn, wb9T, b_out, ybf, bnsum, bnsqs);

  bnfin_kernel<<<1, 256, 0, stream>>>(bnsum, bnsqs, gamma, beta, scale, shift);
  bnapply_kernel<<<2048, 256, 0, stream>>>(ybf, y, scale, shift);
}

// Round 20
// 428.920 us; speedup vs baseline: 1.1246x; 1.1246x over previous
//
#include <hip/hip_runtime.h>
#include <hip/hip_bf16.h>

#define BB 16
#define CC 192
#define HH 96
#define WWW 96
#define HWSZ 9216
#define DKC 64

typedef __hip_bfloat16 bf16;
typedef __attribute__((ext_vector_type(8))) short s8v;
typedef __attribute__((ext_vector_type(4))) float f32x4;

__device__ __forceinline__ float bf2f(unsigned short u) {
  union { unsigned int i; float f; } x; x.i = ((unsigned int)u) << 16; return x.f;
}
__device__ __forceinline__ unsigned short f2bf(float f) {
  union { __hip_bfloat16 h; unsigned short u; } c; c.h = __float2bfloat16(f); return c.u;
}

// ---------------- prep: w_out [oc][c][ky][kx] -> wb9T [sh][oc][c] bf16 ----------------
__global__ __launch_bounds__(256) void prep_w_kernel(const float* __restrict__ w_out,
                                                     unsigned short* __restrict__ wb9T) {
  int e = blockIdx.x * 256 + threadIdx.x;
  if (e >= 9 * CC * CC) return;
  int c = e % CC;
  int oc = (e / CC) % CC;
  int sh = e / (CC * CC);
  wb9T[e] = f2bf(w_out[((size_t)(oc * CC + c)) * 9 + sh]);
}

// ---------------- prep: wq/wk/wv fp32 -> wqkv [sel][oc][c] bf16 ----------------
__global__ __launch_bounds__(256) void prep_wqkv_kernel(
    const float* __restrict__ wq, const float* __restrict__ wk, const float* __restrict__ wv,
    unsigned short* __restrict__ wqkv) {
  int e = blockIdx.x * 256 + threadIdx.x;
  if (e >= 3 * CC * CC) return;
  int sel = e / (CC * CC), r = e % (CC * CC);
  const float* w = sel == 0 ? wq : sel == 1 ? wk : wv;
  wqkv[e] = f2bf(w[r]);
}

// ---------------- x: NCHW fp32 -> NHWC bf16 ----------------
__global__ __launch_bounds__(256) void xcvt_kernel(const float* __restrict__ x,
                                                   unsigned short* __restrict__ xb) {
  __shared__ float xt[CC][65];
  int b = blockIdx.x / 144, tile = blockIdx.x % 144;
  int pix0 = tile * 64;
  const float* xsrc = x + (size_t)b * CC * HWSZ + pix0;
  for (int e = threadIdx.x; e < CC * 16; e += 256) {
    int c = e >> 4, seg = e & 15;
    float4 t4 = *(const float4*)(xsrc + (size_t)c * HWSZ + seg * 4);
    xt[c][seg * 4 + 0] = t4.x; xt[c][seg * 4 + 1] = t4.y;
    xt[c][seg * 4 + 2] = t4.z; xt[c][seg * 4 + 3] = t4.w;
  }
  __syncthreads();
  unsigned short* dst = xb + ((size_t)(b * HWSZ + pix0)) * CC;
  for (int e = threadIdx.x; e < 24 * 64; e += 256) {
    int cg = e >> 6, p = e & 63;
    uint4 ov;
    unsigned short* ou = (unsigned short*)&ov;
    #pragma unroll
    for (int j = 0; j < 8; ++j) ou[j] = f2bf(xt[cg * 8 + j][p]);
    *(uint4*)(dst + (size_t)p * CC + cg * 8) = ov;
  }
}

// ---------------- QKV v5b: block=(b,h); whole x-row in LDS; 3-pass vt epilogue ----------
#define VTS 232
__global__ __launch_bounds__(256) void qkv_mfma_kernel(
    const unsigned short* __restrict__ xb, const unsigned short* __restrict__ wqkv,
    const float* __restrict__ bq, const float* __restrict__ bk, const float* __restrict__ bv,
    unsigned short* __restrict__ q, unsigned short* __restrict__ k,
    unsigned short* __restrict__ v) {
  __shared__ unsigned short xl[96 * 200];   // [pix][192 ch + pad8]  (38400 B)
  __shared__ unsigned short vt[32 * VTS];   // transpose buffer      (14848 B) -> 53 KB total
  const int tid = threadIdx.x;
  const int bid = (blockIdx.x & 7) * 192 + (blockIdx.x >> 3);  // XCD swizzle (1536/8=192)
  const int h = bid % HH;
  const int b = bid / HH;
  const int lane = tid & 63, wid = tid >> 6;
  const int lr = lane & 15, hi8 = (lane >> 4) * 8, rowb = (lane >> 4) * 4;
  const int n0 = wid * 48;
  const unsigned short* xrow = xb + ((size_t)(b * HWSZ + h * WWW)) * CC;

  // stage entire row: 96 pix x 192 ch = 2304 uint4 = 9*256 exactly
  #pragma unroll
  for (int i = 0; i < 9; ++i) {
    int u = tid + i * 256;
    int pix = u / 24, cg = u % 24;
    *(uint4*)(xl + pix * 200 + cg * 8) = *(const uint4*)(xrow + (size_t)pix * CC + cg * 8);
  }
  __syncthreads();

  for (int sel = 0; sel < 3; ++sel) {
    const unsigned short* wsel = wqkv + (size_t)sel * CC * CC;
    f32x4 acc[6][3];
    #pragma unroll
    for (int mt = 0; mt < 6; ++mt)
      #pragma unroll
      for (int nt = 0; nt < 3; ++nt) acc[mt][nt] = (f32x4){0.f, 0.f, 0.f, 0.f};

    auto loadB = [&](int ck, s8v (&dst)[3]) {
      const unsigned short* src = wsel + ck * 32 + hi8;
      #pragma unroll
      for (int nt = 0; nt < 3; ++nt)
        dst[nt] = *(const s8v*)(src + (size_t)(n0 + nt * 16 + lr) * CC);
    };
    auto loadA = [&](int ck, s8v (&dst)[6]) {
      #pragma unroll
      for (int mt = 0; mt < 6; ++mt)
        dst[mt] = *(const s8v*)(xl + (mt * 16 + lr) * 200 + ck * 32 + hi8);
    };
    auto qstep = [&](int ck, s8v (&slot)[3], s8v (&acur)[6], s8v (&anxt)[6]) {
      if (ck < 5) loadA(ck + 1, anxt);
      #pragma unroll
      for (int mt = 0; mt < 6; ++mt)
        #pragma unroll
        for (int nt = 0; nt < 3; ++nt)
          acc[mt][nt] = __builtin_amdgcn_mfma_f32_16x16x32_bf16(acur[mt], slot[nt], acc[mt][nt], 0, 0, 0);
      if (ck + 3 < 6) loadB(ck + 3, slot);
    };

    s8v br0[3], br1[3], br2[3], aA[6], aB[6];
    loadB(0, br0); loadB(1, br1); loadB(2, br2);
    loadA(0, aA);
    qstep(0, br0, aA, aB);
    qstep(1, br1, aB, aA);
    qstep(2, br2, aA, aB);
    qstep(3, br0, aB, aA);
    qstep(4, br1, aA, aB);
    qstep(5, br2, aB, aA);

    // epilogue: bias + 3-pass transpose through vt (32 pixels = 2 frags per pass)
    const float* bsel = (sel == 0 ? bq : sel == 1 ? bk : bv);
    float bias[3];
    #pragma unroll
    for (int nt = 0; nt < 3; ++nt) bias[nt] = bsel[n0 + nt * 16 + lr];
    unsigned short* dst = (sel == 0 ? q : sel == 1 ? k : v) + ((size_t)(b * HWSZ + h * WWW)) * CC;
    #pragma unroll
    for (int pass = 0; pass < 3; ++pass) {
      __syncthreads();  // vt free (previous pass/sel readers done)
      #pragma unroll
      for (int mt2 = 0; mt2 < 2; ++mt2)
        #pragma unroll
        for (int nt = 0; nt < 3; ++nt)
          #pragma unroll
          for (int i = 0; i < 4; ++i)
            vt[(mt2 * 16 + rowb + i) * VTS + n0 + nt * 16 + lr] =
                f2bf(acc[pass * 2 + mt2][nt][i] + bias[nt]);
      __syncthreads();
      #pragma unroll
      for (int ii = 0; ii < 3; ++ii) {
        int e = tid + ii * 256;
        int p = e % 32, cg = e / 32;
        *(uint4*)(dst + (size_t)(pass * 32 + p) * CC + cg * 8) = *(uint4*)(vt + p * VTS + cg * 8);
      }
    }
  }
}

// ---------------- scores via MFMA: P x P GEMM over K=(rs,ch); no LDS, direct gather ------
template <int HS, int WS, int OH, int OW, int IDX>
__global__ __launch_bounds__(256) void scores_mfma_kernel(
    const unsigned short* __restrict__ q, const unsigned short* __restrict__ k,
    float* __restrict__ scores) {
  constexpr int P = HS * WS;
  constexpr int NPOS = OH * OW;
  constexpr int SLABS = 64;
  constexpr int STRIDE = SLABS * 4;
  const int slab = blockIdx.x % SLABS;
  const int b = blockIdx.x / SLABS;
  const int wid = threadIdx.x >> 6;
  const int lane = threadIdx.x & 63;
  const int lr = lane & 15, g8 = (lane >> 4) * 8;
  const int p = (lr < P) ? lr : 0;            // clamp unused rows (same-address broadcast)
  const int pixoff = (p / WS) * WWW + (p % WS);
  const unsigned short* qb = q + (size_t)b * HWSZ * CC + IDX * 64 + g8;
  const unsigned short* kb = k + (size_t)b * HWSZ * CC + IDX * 64 + g8;

  f32x4 acc = (f32x4){0.f, 0.f, 0.f, 0.f};
  int rs = slab * 4 + wid;
  if (rs < NPOS) {
    s8v aq0, aq1, bk0, bk1;
    {
      int r = rs / OW, s = rs - r * OW;
      size_t pix = (size_t)(r * HS * WWW + s * WS + pixoff) * CC;
      aq0 = *(const s8v*)(qb + pix);
      aq1 = *(const s8v*)(qb + pix + 32);
      bk0 = *(const s8v*)(kb + pix);
      bk1 = *(const s8v*)(kb + pix + 32);
    }
    for (;;) {
      int nrs = rs + STRIDE;
      s8v nq0, nq1, nk0, nk1;
      if (nrs < NPOS) {
        int r = nrs / OW, s = nrs - r * OW;
        size_t pix = (size_t)(r * HS * WWW + s * WS + pixoff) * CC;
        nq0 = *(const s8v*)(qb + pix);
        nq1 = *(const s8v*)(qb + pix + 32);
        nk0 = *(const s8v*)(kb + pix);
        nk1 = *(const s8v*)(kb + pix + 32);
      }
      acc = __builtin_amdgcn_mfma_f32_16x16x32_bf16(aq0, bk0, acc, 0, 0, 0);
      acc = __builtin_amdgcn_mfma_f32_16x16x32_bf16(aq1, bk1, acc, 0, 0, 0);
      if (nrs >= NPOS) break;
      aq0 = nq0; aq1 = nq1; bk0 = nk0; bk1 = nk1;
      rs = nrs;
    }
  }
  const int col = lane & 15;
  const int row0 = (lane >> 4) * 4;
  if (col < P) {
    float* sc = scores + (IDX * BB + b) * 256;
    #pragma unroll
    for (int i = 0; i < 4; ++i) {
      int row = row0 + i;
      if (row < P) atomicAdd(sc + row * P + col, acc[i]);
    }
  }
}

// ---------------- softmax over P ----------------
__global__ void softmax_kernel(const float* __restrict__ scores, float* __restrict__ probs) {
  int t = threadIdx.x;
  int idx, b, p, P; float scale;
  if (t < 64)       { idx = 0; b = t >> 2;           p = t & 3;         P = 4;  scale = 1.f / 384.f; }
  else if (t < 208) { int u = t - 64;  idx = 1; b = u / 9;  p = u % 9;  P = 9;  scale = 1.f / 256.f; }
  else if (t < 464) { int u = t - 208; idx = 2; b = u >> 4; p = u & 15; P = 16; scale = 1.f / 192.f; }
  else return;
  const float* row = scores + (idx * BB + b) * 256 + p * P;
  float* orow = probs + (idx * BB + b) * 256 + p * P;
  float vals[16];
  float m = -1e30f;
  for (int i = 0; i < P; i++) { vals[i] = row[i] * scale; m = fmaxf(m, vals[i]); }
  float s = 0.f;
  for (int i = 0; i < P; i++) { vals[i] = expf(vals[i] - m); s += vals[i]; }
  float inv = 1.f / s;
  for (int i = 0; i < P; i++) orow[i] = vals[i] * inv;
}

// ---------------- PV + unstitch: block = (b, r); v/attn NHWC ----------------
template <int HS, int WS, int OH, int OW, int IDX>
__global__ __launch_bounds__(256) void pv_kernel(
    const unsigned short* __restrict__ v, const float* __restrict__ probs,
    unsigned short* __restrict__ attn) {
  constexpr int P = HS * WS;
  __shared__ unsigned short vl[HS * 96 * 72];  // [iq][col][c(64)+pad8]
  __shared__ float pl[P * P];
  int b = blockIdx.x / OH;
  int r = blockIdx.x % OH;
  const int tid = threadIdx.x;
  for (int u = tid; u < HS * 96 * 8; u += 256) {
    int iq = u / 768, w = (u >> 3) % 96, cg = u & 7;
    *(uint4*)(vl + (iq * 96 + w) * 72 + cg * 8) =
        *(const uint4*)(v + ((size_t)(b * HWSZ + (r * HS + iq) * WWW + w)) * CC + IDX * 64 + cg * 8);
  }
  if (tid < P * P) pl[tid] = probs[(IDX * BB + b) * 256 + tid];
  __syncthreads();
  for (int u = tid; u < HS * 96 * 8; u += 256) {
    int i = u / 768, w = (u >> 3) % 96, cg = u & 7;
    int j = w / OW, s = w - j * OW;
    int p = i * WS + j;
    float acc[8];
    #pragma unroll
    for (int m = 0; m < 8; ++m) acc[m] = 0.f;
    #pragma unroll
    for (int iq = 0; iq < HS; ++iq) {
      #pragma unroll
      for (int jq = 0; jq < WS; ++jq) {
        float pw = pl[p * P + iq * WS + jq];
        s8v vv = *(const s8v*)(vl + (iq * 96 + s * WS + jq) * 72 + cg * 8);
        #pragma unroll
        for (int m = 0; m < 8; ++m) acc[m] += pw * bf2f((unsigned short)vv[m]);
      }
    }
    uint4 ov;
    ov.x = (unsigned int)f2bf(acc[0]) | ((unsigned int)f2bf(acc[1]) << 16);
    ov.y = (unsigned int)f2bf(acc[2]) | ((unsigned int)f2bf(acc[3]) << 16);
    ov.z = (unsigned int)f2bf(acc[4]) | ((unsigned int)f2bf(acc[5]) << 16);
    ov.w = (unsigned int)f2bf(acc[6]) | ((unsigned int)f2bf(acc[7]) << 16);
    *(uint4*)(attn + ((size_t)(b * HWSZ + (i * OH + r) * WWW + w)) * CC + IDX * 64 + cg * 8) = ov;
  }
}

// ---------------- conv3x3: single-buffer A (24 KB), B ring-3, no forced bounds ----------
__global__ __launch_bounds__(256) void conv_mfma_kernel(
    const unsigned short* __restrict__ attn, const unsigned short* __restrict__ wb9T,
    const float* __restrict__ b_out, unsigned short* __restrict__ ybf,
    float* __restrict__ bnsum, float* __restrict__ bnsqs) {
  __shared__ unsigned short al[3 * 98 * 40];  // [ky][w+halo][c32 + pad8] = 23520 B
  const int tid = threadIdx.x;
  const int bid = (blockIdx.x & 7) * 192 + (blockIdx.x >> 3);  // XCD swizzle (1536/8=192)
  const int h = bid % HH;
  const int b = bid / HH;
  const int lane = tid & 63, wid = tid >> 6;
  const int lr = lane & 15, hi8 = (lane >> 4) * 8, rowb = (lane >> 4) * 4;
  const int n0 = wid * 48;

  f32x4 acc[6][3];
  #pragma unroll
  for (int mt = 0; mt < 6; ++mt)
    #pragma unroll
    for (int nt = 0; nt < 3; ++nt) acc[mt][nt] = (f32x4){0.f, 0.f, 0.f, 0.f};

  uint4 aregs[5];
  auto stageA_LOAD = [&](int chunk) {
    int c0 = chunk * 32;
    #pragma unroll
    for (int i = 0; i < 5; ++i) {
      int u = tid + i * 256;
      if (u < 1176) {
        int row = u / 392, rem = u % 392, wx = rem >> 2, qq = rem & 3;
        int hr = h + row - 1, w = wx - 1;
        uint4 val = make_uint4(0u, 0u, 0u, 0u);
        if (hr >= 0 && hr < HH && w >= 0 && w < WWW)
          val = *(const uint4*)(attn + ((size_t)(b * HWSZ + hr * WWW + w)) * CC + c0 + qq * 8);
        aregs[i] = val;
      }
    }
  };
  auto stageA_WRITE = [&]() {
    #pragma unroll
    for (int i = 0; i < 5; ++i) {
      int u = tid + i * 256;
      if (u < 1176) {
        int row = u / 392, rem = u % 392, wx = rem >> 2, qq = rem & 3;
        *(uint4*)(al + (row * 98 + wx) * 40 + qq * 8) = aregs[i];
      }
    }
  };
  auto loadB = [&](int it2, s8v (&dst)[3]) {
    int chunk = it2 / 9, sh = it2 % 9;
    const unsigned short* src = wb9T + (size_t)sh * CC * CC + chunk * 32 + hi8;
    #pragma unroll
    for (int nt = 0; nt < 3; ++nt)
      dst[nt] = *(const s8v*)(src + (size_t)(n0 + nt * 16 + lr) * CC);
  };

  s8v br0[3], br1[3], br2[3];
  stageA_LOAD(0);
  stageA_WRITE();
  loadB(0, br0); loadB(1, br1); loadB(2, br2);
  __syncthreads();

  auto step = [&](int chunk, int sh, s8v (&slot)[3]) {
    if (sh == 0 && chunk < 5) stageA_LOAD(chunk + 1);
    int ky = sh / 3, kx = sh % 3;
    s8v a[6];
    #pragma unroll
    for (int mt = 0; mt < 6; ++mt)
      a[mt] = *(const s8v*)(al + (ky * 98 + mt * 16 + lr + kx) * 40 + hi8);
    #pragma unroll
    for (int mt = 0; mt < 6; ++mt)
      #pragma unroll
      for (int nt = 0; nt < 3; ++nt)
        acc[mt][nt] = __builtin_amdgcn_mfma_f32_16x16x32_bf16(a[mt], slot[nt], acc[mt][nt], 0, 0, 0);
    int it = chunk * 9 + sh;
    if (it + 3 < 54) loadB(it + 3, slot);
  };

  for (int chunk = 0; chunk < 6; ++chunk) {
    step(chunk, 0, br0);
    step(chunk, 1, br1);
    step(chunk, 2, br2);
    step(chunk, 3, br0);
    step(chunk, 4, br1);
    step(chunk, 5, br2);
    step(chunk, 6, br0);
    step(chunk, 7, br1);
    step(chunk, 8, br2);
    if (chunk < 5) {
      __syncthreads();        // all waves done reading al for this chunk
      stageA_WRITE();         // overwrite with next chunk
      __syncthreads();        // writes visible
    }
  }

  // epilogue: bias, bf16 y store (NCHW), BN partial sums
  #pragma unroll
  for (int nt = 0; nt < 3; ++nt) {
    int oc = n0 + nt * 16 + lr;
    float bias = b_out[oc];
    float s1 = 0.f, s2 = 0.f;
    #pragma unroll
    for (int mt = 0; mt < 6; ++mt) {
      float v0 = acc[mt][nt][0] + bias;
      float v1 = acc[mt][nt][1] + bias;
      float v2 = acc[mt][nt][2] + bias;
      float v3 = acc[mt][nt][3] + bias;
      s1 += v0 + v1 + v2 + v3;
      s2 += v0 * v0 + v1 * v1 + v2 * v2 + v3 * v3;
      uint2 pk;
      pk.x = (unsigned int)f2bf(v0) | ((unsigned int)f2bf(v1) << 16);
      pk.y = (unsigned int)f2bf(v2) | ((unsigned int)f2bf(v3) << 16);
      *(uint2*)(ybf + ((size_t)(b * CC + oc)) * HWSZ + h * WWW + mt * 16 + rowb) = pk;
    }
    s1 += __shfl_down(s1, 32);
    s1 += __shfl_down(s1, 16);
    s2 += __shfl_down(s2, 32);
    s2 += __shfl_down(s2, 16);
    if (lane < 16) {
      atomicAdd(bnsum + oc, s1);
      atomicAdd(bnsqs + oc, s2);
    }
  }
}

// ---------------- BN finalize ----------------
__global__ void bnfin_kernel(const float* __restrict__ bnsum, const float* __restrict__ bnsqs,
                             const float* __restrict__ gamma, const float* __restrict__ beta,
                             float* __restrict__ scale, float* __restrict__ shift) {
  int c = threadIdx.x;
  if (c >= CC) return;
  const float n = 16.f * 9216.f;
  float mean = bnsum[c] / n;
  float var = bnsqs[c] / n - mean * mean;
  float inv = rsqrtf(var + 1e-5f);
  float sc = gamma[c] * inv;
  scale[c] = sc;
  shift[c] = beta[c] - mean * sc;
}

// ---------------- BN apply + LeakyReLU: ybf bf16 -> d_out fp32 ----------------
__global__ __launch_bounds__(256) void bnapply_kernel(const unsigned short* __restrict__ ybf,
                                                      float* __restrict__ y,
                                                      const float* __restrict__ scale,
                                                      const float* __restrict__ shift) {
  const int total8 = BB * CC * HWSZ / 8;
  for (int e = blockIdx.x * 256 + threadIdx.x; e < total8; e += gridDim.x * 256) {
    uint4 t = ((const uint4*)ybf)[e];
    const unsigned short* u = (const unsigned short*)&t;
    int oc = (e / (HWSZ / 8)) % CC;
    float sc = scale[oc], sh = shift[oc];
    float4 o0, o1;
    float w;
    w = bf2f(u[0]) * sc + sh; o0.x = w >= 0.f ? w : 0.2f * w;
    w = bf2f(u[1]) * sc + sh; o0.y = w >= 0.f ? w : 0.2f * w;
    w = bf2f(u[2]) * sc + sh; o0.z = w >= 0.f ? w : 0.2f * w;
    w = bf2f(u[3]) * sc + sh; o0.w = w >= 0.f ? w : 0.2f * w;
    w = bf2f(u[4]) * sc + sh; o1.x = w >= 0.f ? w : 0.2f * w;
    w = bf2f(u[5]) * sc + sh; o1.y = w >= 0.f ? w : 0.2f * w;
    w = bf2f(u[6]) * sc + sh; o1.z = w >= 0.f ? w : 0.2f * w;
    w = bf2f(u[7]) * sc + sh; o1.w = w >= 0.f ? w : 0.2f * w;
    ((float4*)y)[e * 2] = o0;
    ((float4*)y)[e * 2 + 1] = o1;
  }
}

extern "C" void kernel_launch(void* const* d_in, const int* in_sizes, int n_in,
                              void* d_out, int out_size, void* d_ws, size_t ws_size,
                              hipStream_t stream) {
  const float* x     = (const float*)d_in[0];
  const float* wq    = (const float*)d_in[1];
  const float* bq    = (const float*)d_in[2];
  const float* wk    = (const float*)d_in[3];
  const float* bk    = (const float*)d_in[4];
  const float* wv    = (const float*)d_in[5];
  const float* bv    = (const float*)d_in[6];
  const float* w_out = (const float*)d_in[7];
  const float* b_out = (const float*)d_in[8];
  const float* gamma = (const float*)d_in[9];
  const float* beta  = (const float*)d_in[10];

  char* ws = (char*)d_ws;
  const size_t TB = (size_t)BB * CC * HWSZ * sizeof(bf16);   // 56,623,104 B per tensor
  unsigned short* q    = (unsigned short*)(ws);               // NHWC bf16; later reused as ybf
  unsigned short* ybf  = q;                                   // y bf16 NCHW (q dead after scores)
  unsigned short* k    = (unsigned short*)(ws + TB);          // NHWC bf16
  unsigned short* v    = (unsigned short*)(ws + 2 * TB);      // NHWC bf16
  unsigned short* attn = (unsigned short*)(ws + 3 * TB);      // NHWC bf16; ALSO aliases xb
  unsigned short* xb   = attn;                                // x NHWC bf16 (dead before pv writes attn)
  unsigned short* wb9T = (unsigned short*)(ws + 4 * TB);      // [9][192][192] bf16
  unsigned short* wqkv = (unsigned short*)(ws + 4 * TB + 663552);  // [3][192][192] bf16
  float* scores = (float*)(ws + 4 * TB + 663552 + 221184);
  float* bnsum  = scores + 3 * BB * 256;
  float* bnsqs  = bnsum + CC;
  float* probs  = bnsqs + CC;
  float* scale  = probs + 3 * BB * 256;
  float* shift  = scale + CC;
  float* y = (float*)d_out;

  // zero scores + bn partials (contiguous)
  hipMemsetAsync(scores, 0, 49152 + 2 * CC * 4, stream);

  prep_w_kernel<<<(9 * CC * CC + 255) / 256, 256, 0, stream>>>(w_out, wb9T);
  prep_wqkv_kernel<<<(3 * CC * CC + 255) / 256, 256, 0, stream>>>(wq, wk, wv, wqkv);

  xcvt_kernel<<<BB * 144, 256, 0, stream>>>(x, xb);
  qkv_mfma_kernel<<<BB * HH, 256, 0, stream>>>(xb, wqkv, bq, bk, bv, q, k, v);

  scores_mfma_kernel<2, 2, 48, 48, 0><<<BB * 64, 256, 0, stream>>>(q, k, scores);
  scores_mfma_kernel<3, 3, 32, 32, 1><<<BB * 64, 256, 0, stream>>>(q, k, scores);
  scores_mfma_kernel<4, 4, 24, 24, 2><<<BB * 64, 256, 0, stream>>>(q, k, scores);

  softmax_kernel<<<1, 512, 0, stream>>>(scores, probs);

  pv_kernel<2, 2, 48, 48, 0><<<BB * 48, 256, 0, stream>>>(v, probs, attn);
  pv_kernel<3, 3, 32, 32, 1><<<BB * 32, 256, 0, stream>>>(v, probs, attn);
  pv_kernel<4, 4, 24, 24, 2><<<BB * 24, 256, 0, stream>>>(v, probs, attn);

  conv_mfma_kernel<<<BB * HH, 256, 0, stream>>>(attn, wb9T, b_out, ybf, bnsum, bnsqs);

  bnfin_kernel<<<1, 256, 0, stream>>>(bnsum, bnsqs, gamma, beta, scale, shift);
  bnapply_kernel<<<2048, 256, 0, stream>>>(ybf, y, scale, shift);
}